// Round 6
// baseline (34.504 us; speedup 1.0000x reference)
//
#include <hip/hip_runtime.h>
#include <hip/hip_bf16.h>

#define T_LEN 2048
#define D_DIM 128
#define K_DIM 2048
#define M_DIM 8192
#define LOOKUP 101
#define HWIN 50

typedef __attribute__((ext_vector_type(8))) short short8;
typedef __attribute__((ext_vector_type(4))) float f32x4;

static __device__ __forceinline__ unsigned int f2bf(float f) {
  unsigned int u = __float_as_uint(f);
  return (u + 0x7fffu + ((u >> 16) & 1u)) >> 16;  // RNE bf16 bits
}

static __device__ __forceinline__ short8 pack8(float4 lo, float4 hi) {
  uint4 u;
  u.x = f2bf(lo.x) | (f2bf(lo.y) << 16);
  u.y = f2bf(lo.z) | (f2bf(lo.w) << 16);
  u.z = f2bf(hi.x) | (f2bf(hi.y) << 16);
  u.w = f2bf(hi.z) | (f2bf(hi.w) << 16);
  return *(short8*)&u;
}

// ---- Kernel 1: W [2048][128] f32 -> Bp fragment-packed bf16 (512 KB) ----
// Bp granule (ks, ct, lane) 16B = bf16 of W[ks*32 + (lane>>4)*8 + j][ct*16 + (lane&15)], j=0..7
__global__ __launch_bounds__(256) void k_pack(const float* __restrict__ W,
                                              unsigned short* __restrict__ Bp) {
  __shared__ float sw[32][132];
  const int ks = blockIdx.x;  // 0..63
  const int t = threadIdx.x;
  const float* src = W + (size_t)ks * 32 * D_DIM;
#pragma unroll
  for (int j = 0; j < 4; ++j) {
    int idx = t + j * 256;
    int row = idx >> 5, c4 = idx & 31;
    float4 v = *(const float4*)(src + row * D_DIM + c4 * 4);
    *(float4*)&sw[row][c4 * 4] = v;
  }
  __syncthreads();
#pragma unroll
  for (int e = 0; e < 2; ++e) {
    int f = t * 2 + e;
    int ct = f >> 6, l = f & 63;
    int kr = (l >> 4) * 8, col = ct * 16 + (l & 15);
    uint4 o;
    o.x = f2bf(sw[kr + 0][col]) | (f2bf(sw[kr + 1][col]) << 16);
    o.y = f2bf(sw[kr + 2][col]) | (f2bf(sw[kr + 3][col]) << 16);
    o.z = f2bf(sw[kr + 4][col]) | (f2bf(sw[kr + 5][col]) << 16);
    o.w = f2bf(sw[kr + 6][col]) | (f2bf(sw[kr + 7][col]) << 16);
    *(uint4*)(Bp + (((size_t)(ks * 8 + ct) << 6) + l) * 8) = o;
  }
}

// ---- Kernel 2: K-split-8 GEMM, register-direct (no LDS in main loop) ----
// 512 blocks x 512 thr (8 waves). Wave wv: rows r0..r0+15, k in [wv*256,+256) = 8 steps of 32.
// Swapped operands: a-frag = W (from packed Bp, contiguous), b-frag = x loaded DIRECTLY
// into fragment registers (lane's 8 consecutive k = 2 x dwordx4), D = C^T fragments.
__global__ __launch_bounds__(512, 4) void k_gemm(const float* __restrict__ X,
                                                 const unsigned short* __restrict__ Bp,
                                                 const float* __restrict__ bias,
                                                 unsigned short* __restrict__ Pn) {
  __shared__ __align__(16) unsigned char Pw[8 * 8192];  // 64 KiB partials
  const int tid = threadIdx.x;
  const int lane = tid & 63;
  const int wv = tid >> 6;
  const int r0 = blockIdx.x * 16;
  const int l15 = lane & 15;
  const int kg = lane >> 4;

  // x fragment source: row = r0+l15, k = wv*256 + s*32 + kg*8 + h*4
  const float* xb = X + (size_t)(r0 + l15) * K_DIM + wv * 256 + kg * 8;

  f32x4 acc[8];
#pragma unroll
  for (int i = 0; i < 8; ++i) acc[i] = (f32x4){0.f, 0.f, 0.f, 0.f};

  float4 xc[2];
  short8 wc[8];
  xc[0] = *(const float4*)(xb);
  xc[1] = *(const float4*)(xb + 4);
#pragma unroll
  for (int ct = 0; ct < 8; ++ct)
    wc[ct] = *(const short8*)(Bp + (((size_t)(wv * 8) * 8 + ct) * 64 + lane) * 8);

#pragma unroll
  for (int s = 0; s < 8; ++s) {
    float4 xn[2];
    short8 wn[8];
    if (s < 7) {
      xn[0] = *(const float4*)(xb + (s + 1) * 32);
      xn[1] = *(const float4*)(xb + (s + 1) * 32 + 4);
#pragma unroll
      for (int ct = 0; ct < 8; ++ct)
        wn[ct] = *(const short8*)(Bp + (((size_t)(wv * 8 + s + 1) * 8 + ct) * 64 + lane) * 8);
    }
    short8 xf = pack8(xc[0], xc[1]);
#pragma unroll
    for (int ct = 0; ct < 8; ++ct)
      acc[ct] = __builtin_amdgcn_mfma_f32_16x16x32_bf16(wc[ct], xf, acc[ct], 0, 0, 0);
    if (s < 7) {
      xc[0] = xn[0]; xc[1] = xn[1];
#pragma unroll
      for (int ct = 0; ct < 8; ++ct) wc[ct] = wn[ct];
    }
  }

  // partials: D^T fragment -> Pw[wv][xrow=l15][wcol], XOR-swizzled (bits 4-6) for banks
  unsigned char* pwb = Pw + wv * 8192;
#pragma unroll
  for (int ct = 0; ct < 8; ++ct) {
    int byte = l15 * 512 + ((ct * 64 + kg * 16) ^ ((l15 & 7) << 4));
    *(float4*)(pwb + byte) = make_float4(acc[ct][0], acc[ct][1], acc[ct][2], acc[ct][3]);
  }
  __syncthreads();

  // reduce 8 partials + bias + row-normalize + store bf16
  const int row = tid >> 5;      // 0..15
  const int c4 = tid & 31;       // 16B chunk of the 128-col row
  const int rbyte = row * 512 + ((c4 * 16) ^ ((row & 7) << 4));
  float4 tot = make_float4(0.f, 0.f, 0.f, 0.f);
#pragma unroll
  for (int q = 0; q < 8; ++q) {
    float4 v = *(const float4*)(Pw + q * 8192 + rbyte);
    tot.x += v.x; tot.y += v.y; tot.z += v.z; tot.w += v.w;
  }
  float4 bv = *(const float4*)(bias + c4 * 4);
  tot.x += bv.x; tot.y += bv.y; tot.z += bv.z; tot.w += bv.w;
  float ss = tot.x * tot.x + tot.y * tot.y + tot.z * tot.z + tot.w * tot.w;
  ss += __shfl_xor(ss, 1);
  ss += __shfl_xor(ss, 2);
  ss += __shfl_xor(ss, 4);
  ss += __shfl_xor(ss, 8);
  ss += __shfl_xor(ss, 16);
  float sc = 1.0f / fmaxf(sqrtf(ss), 1e-12f);
  unsigned int p0 = f2bf(tot.x * sc) | (f2bf(tot.y * sc) << 16);
  unsigned int p1 = f2bf(tot.z * sc) | (f2bf(tot.w * sc) << 16);
  *(uint2*)(Pn + (size_t)(r0 + row) * D_DIM + c4 * 4) = make_uint2(p0, p1);
}

// ---------------- Kernel 3: banded similarity via MFMA ----------------
#define SROWS 144

__global__ __launch_bounds__(256) void k_sim(const unsigned short* __restrict__ Pn,
                                             float* __restrict__ out) {
  __shared__ unsigned short sm[SROWS * D_DIM];  // 36 KiB, XOR-swizzled 8-short groups
  const int bb = blockIdx.x >> 6;
  const int tb = blockIdx.x & 63;
  const int t0 = tb * 32;
  const int tid = threadIdx.x;

  for (int idx = tid; idx < SROWS * 16; idx += 256) {
    int i = idx >> 4, seg = idx & 15;
    int t = t0 - HWIN + i;
    uint4 val = make_uint4(0u, 0u, 0u, 0u);
    if (t >= 0 && t < T_LEN)
      val = *(const uint4*)(Pn + ((size_t)bb * T_LEN + t) * D_DIM + seg * 8);
    *(uint4*)&sm[i * D_DIM + ((seg ^ (i & 7)) << 3)] = val;
  }
  __syncthreads();

  const int lane = tid & 63;
  const int wv = tid >> 6;
  const int l15 = lane & 15;
  const int kg = lane >> 4;
  const int rt = wv >> 1;
  const int itp = wv & 1;

  short8 af[4];
  const int ia = HWIN + rt * 16 + l15;
#pragma unroll
  for (int ks = 0; ks < 4; ++ks) {
    int g = ks * 4 + kg;
    af[ks] = *(const short8*)&sm[ia * D_DIM + ((g ^ (ia & 7)) << 3)];
  }

  for (int it = itp; it < 9; it += 2) {
    f32x4 acc = (f32x4){0.f, 0.f, 0.f, 0.f};
    const int ib = it * 16 + l15;
#pragma unroll
    for (int ks = 0; ks < 4; ++ks) {
      int g = ks * 4 + kg;
      short8 bf = *(const short8*)&sm[ib * D_DIM + ((g ^ (ib & 7)) << 3)];
      acc = __builtin_amdgcn_mfma_f32_16x16x32_bf16(af[ks], bf, acc, 0, 0, 0);
    }
#pragma unroll
    for (int j = 0; j < 4; ++j) {
      int r = rt * 16 + kg * 4 + j;
      int w = ib - r;
      if (w >= 0 && w <= 100)
        out[((size_t)bb * T_LEN + t0 + r) * LOOKUP + w] = acc[j];
    }
  }
}

extern "C" void kernel_launch(void* const* d_in, const int* in_sizes, int n_in,
                              void* d_out, int out_size, void* d_ws, size_t ws_size,
                              hipStream_t stream) {
  (void)in_sizes; (void)n_in; (void)out_size; (void)ws_size;
  const float* x = (const float*)d_in[0];
  const float* W = (const float*)d_in[1];
  const float* b = (const float*)d_in[2];
  float* out = (float*)d_out;
  unsigned short* Bp = (unsigned short*)d_ws;            // 512 KiB fragment-packed W
  unsigned short* Pn = Bp + (size_t)D_DIM * K_DIM;       // 8192*128 bf16 = 2 MiB

  k_pack<<<64, 256, 0, stream>>>(W, Bp);
  k_gemm<<<M_DIM / 16, 512, 0, stream>>>(x, Bp, b, Pn);
  k_sim<<<4 * (T_LEN / 32), 256, 0, stream>>>(Pn, out);
}

// Round 7
// 32.907 us; speedup vs baseline: 1.0485x; 1.0485x over previous
//
#include <hip/hip_runtime.h>
#include <hip/hip_bf16.h>

#define T_LEN 2048
#define D_DIM 128
#define K_DIM 2048
#define M_DIM 8192
#define LOOKUP 101
#define HWIN 50

typedef __attribute__((ext_vector_type(8))) short short8;
typedef __attribute__((ext_vector_type(4))) float f32x4;

static __device__ __forceinline__ unsigned int f2bf(float f) {
  unsigned int u = __float_as_uint(f);
  return (u + 0x7fffu + ((u >> 16) & 1u)) >> 16;  // RNE bf16 bits
}

static __device__ __forceinline__ short8 pack8(float4 lo, float4 hi) {
  uint4 u;
  u.x = f2bf(lo.x) | (f2bf(lo.y) << 16);
  u.y = f2bf(lo.z) | (f2bf(lo.w) << 16);
  u.z = f2bf(hi.x) | (f2bf(hi.y) << 16);
  u.w = f2bf(hi.z) | (f2bf(hi.w) << 16);
  return *(short8*)&u;
}

// ---- Kernel 1: W [2048][128] f32 -> Bp fragment-packed bf16 (512 KB) ----
// Bp granule (ks, ct, lane) 16B = bf16 of W[ks*32 + (lane>>4)*8 + j][ct*16 + (lane&15)], j=0..7
__global__ __launch_bounds__(256) void k_pack(const float* __restrict__ W,
                                              unsigned short* __restrict__ Bp) {
  __shared__ float sw[32][132];
  const int ks = blockIdx.x;  // 0..63
  const int t = threadIdx.x;
  const float* src = W + (size_t)ks * 32 * D_DIM;
#pragma unroll
  for (int j = 0; j < 4; ++j) {
    int idx = t + j * 256;
    int row = idx >> 5, c4 = idx & 31;
    float4 v = *(const float4*)(src + row * D_DIM + c4 * 4);
    *(float4*)&sw[row][c4 * 4] = v;
  }
  __syncthreads();
#pragma unroll
  for (int e = 0; e < 2; ++e) {
    int f = t * 2 + e;
    int ct = f >> 6, l = f & 63;
    int kr = (l >> 4) * 8, col = ct * 16 + (l & 15);
    uint4 o;
    o.x = f2bf(sw[kr + 0][col]) | (f2bf(sw[kr + 1][col]) << 16);
    o.y = f2bf(sw[kr + 2][col]) | (f2bf(sw[kr + 3][col]) << 16);
    o.z = f2bf(sw[kr + 4][col]) | (f2bf(sw[kr + 5][col]) << 16);
    o.w = f2bf(sw[kr + 6][col]) | (f2bf(sw[kr + 7][col]) << 16);
    *(uint4*)(Bp + (((size_t)(ks * 8 + ct) << 6) + l) * 8) = o;
  }
}

// ---- Kernel 2: 32 rows/wave register-direct GEMM, K-split-8, 2-stage LDS reduce ----
// 256 blocks x 512 thr (8 waves). Block owns 32 rows; wave wv: k in [wv*256,+256) = 8 steps.
// Per step: 8 contiguous-1KB W-frag loads (Bp) + 4 x-row-frag loads -> 16 MFMA.
__global__ __launch_bounds__(512, 2) void k_gemm(const float* __restrict__ X,
                                                 const unsigned short* __restrict__ Bp,
                                                 const float* __restrict__ bias,
                                                 unsigned short* __restrict__ Pn) {
  __shared__ __align__(16) unsigned char Pw[4 * 16384];  // 64 KiB: 4 partial buffers
  const int tid = threadIdx.x;
  const int lane = tid & 63;
  const int wv = tid >> 6;
  const int r0 = blockIdx.x * 32;
  const int l15 = lane & 15;
  const int kg = lane >> 4;

  const float* xb0 = X + (size_t)(r0 + l15) * K_DIM + wv * 256 + kg * 8;
  const float* xb1 = xb0 + (size_t)16 * K_DIM;

  f32x4 acc[2][8];
#pragma unroll
  for (int g = 0; g < 2; ++g)
#pragma unroll
    for (int i = 0; i < 8; ++i) acc[g][i] = (f32x4){0.f, 0.f, 0.f, 0.f};

  float4 xc[2][2], xn[2][2];
  short8 wc[8], wn[8];

  xc[0][0] = *(const float4*)(xb0);
  xc[0][1] = *(const float4*)(xb0 + 4);
  xc[1][0] = *(const float4*)(xb1);
  xc[1][1] = *(const float4*)(xb1 + 4);
#pragma unroll
  for (int ct = 0; ct < 8; ++ct)
    wc[ct] = *(const short8*)(Bp + (((size_t)(wv * 8) * 8 + ct) * 64 + lane) * 8);

#pragma unroll
  for (int s = 0; s < 8; ++s) {
    if (s < 7) {
      xn[0][0] = *(const float4*)(xb0 + (s + 1) * 32);
      xn[0][1] = *(const float4*)(xb0 + (s + 1) * 32 + 4);
      xn[1][0] = *(const float4*)(xb1 + (s + 1) * 32);
      xn[1][1] = *(const float4*)(xb1 + (s + 1) * 32 + 4);
#pragma unroll
      for (int ct = 0; ct < 8; ++ct)
        wn[ct] = *(const short8*)(Bp + (((size_t)(wv * 8 + s + 1) * 8 + ct) * 64 + lane) * 8);
    }
    short8 xf0 = pack8(xc[0][0], xc[0][1]);
    short8 xf1 = pack8(xc[1][0], xc[1][1]);
#pragma unroll
    for (int ct = 0; ct < 8; ++ct)
      acc[0][ct] = __builtin_amdgcn_mfma_f32_16x16x32_bf16(wc[ct], xf0, acc[0][ct], 0, 0, 0);
#pragma unroll
    for (int ct = 0; ct < 8; ++ct)
      acc[1][ct] = __builtin_amdgcn_mfma_f32_16x16x32_bf16(wc[ct], xf1, acc[1][ct], 0, 0, 0);
    if (s < 7) {
      xc[0][0] = xn[0][0]; xc[0][1] = xn[0][1];
      xc[1][0] = xn[1][0]; xc[1][1] = xn[1][1];
#pragma unroll
      for (int ct = 0; ct < 8; ++ct) wc[ct] = wn[ct];
    }
  }

  // ---- two-stage reduce over the 8 K-slices ----
  // acc[rg][ct][j] = partial_p[row = rg*16 + l15][col = ct*16 + kg*4 + j]
  // stage 1a: waves 4..7 write their partials to buffer (wv-4)
  if (wv >= 4) {
    unsigned char* pb = Pw + (wv - 4) * 16384;
#pragma unroll
    for (int rg = 0; rg < 2; ++rg)
#pragma unroll
      for (int ct = 0; ct < 8; ++ct) {
        int byte = (rg * 16 + l15) * 512 + ((ct * 64 + kg * 16) ^ ((l15 & 7) << 4));
        *(float4*)(pb + byte) = make_float4(acc[rg][ct][0], acc[rg][ct][1], acc[rg][ct][2], acc[rg][ct][3]);
      }
  }
  __syncthreads();
  // stage 1b: waves 0..3 add into buffer wv
  if (wv < 4) {
    unsigned char* pb = Pw + wv * 16384;
#pragma unroll
    for (int rg = 0; rg < 2; ++rg)
#pragma unroll
      for (int ct = 0; ct < 8; ++ct) {
        int byte = (rg * 16 + l15) * 512 + ((ct * 64 + kg * 16) ^ ((l15 & 7) << 4));
        float4 v = *(float4*)(pb + byte);
        v.x += acc[rg][ct][0]; v.y += acc[rg][ct][1];
        v.z += acc[rg][ct][2]; v.w += acc[rg][ct][3];
        *(float4*)(pb + byte) = v;
      }
  }
  __syncthreads();

  // stage 2: reduce 4 buffers + bias + row-normalize + store bf16
  const int row = tid >> 4;      // 0..31
  const int c8 = tid & 15;       // 8-col chunk
  float tot[8];
#pragma unroll
  for (int i = 0; i < 8; ++i) tot[i] = 0.f;
#pragma unroll
  for (int q = 0; q < 4; ++q)
#pragma unroll
    for (int h = 0; h < 2; ++h) {
      int byte = q * 16384 + row * 512 + (((c8 * 32 + h * 16)) ^ ((row & 7) << 4));
      float4 v = *(const float4*)(Pw + byte);
      tot[h * 4 + 0] += v.x; tot[h * 4 + 1] += v.y;
      tot[h * 4 + 2] += v.z; tot[h * 4 + 3] += v.w;
    }
  float4 bv0 = *(const float4*)(bias + c8 * 8);
  float4 bv1 = *(const float4*)(bias + c8 * 8 + 4);
  tot[0] += bv0.x; tot[1] += bv0.y; tot[2] += bv0.z; tot[3] += bv0.w;
  tot[4] += bv1.x; tot[5] += bv1.y; tot[6] += bv1.z; tot[7] += bv1.w;
  float ss = 0.f;
#pragma unroll
  for (int i = 0; i < 8; ++i) ss += tot[i] * tot[i];
  ss += __shfl_xor(ss, 1);
  ss += __shfl_xor(ss, 2);
  ss += __shfl_xor(ss, 4);
  ss += __shfl_xor(ss, 8);
  float sc = 1.0f / fmaxf(sqrtf(ss), 1e-12f);
  uint4 o;
  o.x = f2bf(tot[0] * sc) | (f2bf(tot[1] * sc) << 16);
  o.y = f2bf(tot[2] * sc) | (f2bf(tot[3] * sc) << 16);
  o.z = f2bf(tot[4] * sc) | (f2bf(tot[5] * sc) << 16);
  o.w = f2bf(tot[6] * sc) | (f2bf(tot[7] * sc) << 16);
  *(uint4*)(Pn + (size_t)(r0 + row) * D_DIM + c8 * 8) = o;
}

// ---------------- Kernel 3: banded similarity via MFMA ----------------
#define SROWS 144

__global__ __launch_bounds__(256) void k_sim(const unsigned short* __restrict__ Pn,
                                             float* __restrict__ out) {
  __shared__ unsigned short sm[SROWS * D_DIM];  // 36 KiB, XOR-swizzled 8-short groups
  const int bb = blockIdx.x >> 6;
  const int tb = blockIdx.x & 63;
  const int t0 = tb * 32;
  const int tid = threadIdx.x;

  for (int idx = tid; idx < SROWS * 16; idx += 256) {
    int i = idx >> 4, seg = idx & 15;
    int t = t0 - HWIN + i;
    uint4 val = make_uint4(0u, 0u, 0u, 0u);
    if (t >= 0 && t < T_LEN)
      val = *(const uint4*)(Pn + ((size_t)bb * T_LEN + t) * D_DIM + seg * 8);
    *(uint4*)&sm[i * D_DIM + ((seg ^ (i & 7)) << 3)] = val;
  }
  __syncthreads();

  const int lane = tid & 63;
  const int wv = tid >> 6;
  const int l15 = lane & 15;
  const int kg = lane >> 4;
  const int rt = wv >> 1;
  const int itp = wv & 1;

  short8 af[4];
  const int ia = HWIN + rt * 16 + l15;
#pragma unroll
  for (int ks = 0; ks < 4; ++ks) {
    int g = ks * 4 + kg;
    af[ks] = *(const short8*)&sm[ia * D_DIM + ((g ^ (ia & 7)) << 3)];
  }

  for (int it = itp; it < 9; it += 2) {
    f32x4 acc = (f32x4){0.f, 0.f, 0.f, 0.f};
    const int ib = it * 16 + l15;
#pragma unroll
    for (int ks = 0; ks < 4; ++ks) {
      int g = ks * 4 + kg;
      short8 bf = *(const short8*)&sm[ib * D_DIM + ((g ^ (ib & 7)) << 3)];
      acc = __builtin_amdgcn_mfma_f32_16x16x32_bf16(af[ks], bf, acc, 0, 0, 0);
    }
#pragma unroll
    for (int j = 0; j < 4; ++j) {
      int r = rt * 16 + kg * 4 + j;
      int w = ib - r;
      if (w >= 0 && w <= 100)
        out[((size_t)bb * T_LEN + t0 + r) * LOOKUP + w] = acc[j];
    }
  }
}

extern "C" void kernel_launch(void* const* d_in, const int* in_sizes, int n_in,
                              void* d_out, int out_size, void* d_ws, size_t ws_size,
                              hipStream_t stream) {
  (void)in_sizes; (void)n_in; (void)out_size; (void)ws_size;
  const float* x = (const float*)d_in[0];
  const float* W = (const float*)d_in[1];
  const float* b = (const float*)d_in[2];
  float* out = (float*)d_out;
  unsigned short* Bp = (unsigned short*)d_ws;            // 512 KiB fragment-packed W
  unsigned short* Pn = Bp + (size_t)D_DIM * K_DIM;       // 8192*128 bf16 = 2 MiB

  k_pack<<<64, 256, 0, stream>>>(W, Bp);
  k_gemm<<<M_DIM / 32, 512, 0, stream>>>(x, Bp, b, Pn);
  k_sim<<<4 * (T_LEN / 32), 256, 0, stream>>>(Pn, out);
}